// Round 4
// baseline (683.621 us; speedup 1.0000x reference)
//
#include <hip/hip_runtime.h>
#include <hip/hip_bf16.h>

#define MQ 65536
#define NKEY 65536
#define KNB 16
#define CCH 64
#define TPB 8   // tiles (of 16 queries) per cross_attn block

typedef _Float16 half8  __attribute__((ext_vector_type(8)));
typedef _Float16 half4v __attribute__((ext_vector_type(4)));
typedef float    floatx4 __attribute__((ext_vector_type(4)));

// ws layout:
//   qp_h [MQ*64] f16, kp_h [NKEY*64] f16, res_g [MQ*64] f16,
//   w4 [4*64*72] f16 (Wg1T,Wg2T,WvT,WtT; transposed, row stride 72),
//   mask_packed [MQ] u16 (bit kn = mask[query][kn]), mflag int

// ---------------- mask dtype detect (1 block) ----------------
__global__ void detect_mask(const unsigned char* __restrict__ m, int* __restrict__ flag)
{
    __shared__ int sflags;
    if (threadIdx.x == 0) sflags = 0;
    __syncthreads();
    const uint4* m4 = (const uint4*)m;
    unsigned int orw = 0;
    #pragma unroll
    for (int it = 0; it < 4; ++it) {
        uint4 v = m4[threadIdx.x + it * 256];
        orw |= v.x | v.y | v.z | v.w;
    }
    int local = 0;
    if (orw & 0x000000FFu) local |= 1;   // pos%4==0 nonzero (int32)
    if (orw & 0x0000FF00u) local |= 2;   // pos%4==1 nonzero (byte-bool)
    if (orw & 0xFFFF0000u) local |= 4;   // pos%4 in {2,3} (float32)
    if (local) atomicOr(&sflags, local);
    __syncthreads();
    if (threadIdx.x == 0) *flag = sflags;
}

// ---------------- proj + mask-pack + weight conversion ----------------
__global__ __launch_bounds__(256, 4)
void proj_prep(const float* __restrict__ q, const float* __restrict__ qpos,
               const float* __restrict__ k, const float* __restrict__ kpos,
               const float* __restrict__ Wqk, const float* __restrict__ bqk,
               const float* __restrict__ Wg1, const float* __restrict__ Wg2,
               const float* __restrict__ Wv,  const float* __restrict__ Wt,
               const unsigned char* __restrict__ maskraw, const int* __restrict__ mflag,
               _Float16* __restrict__ qp_h, _Float16* __restrict__ kp_h,
               _Float16* __restrict__ w4, unsigned short* __restrict__ mask_packed)
{
    const int tid = threadIdx.x;
    const int bid = blockIdx.x;

    if (bid >= 1024) {
        if (bid < 1088) {
            // ---- mask packing: 64 blocks x 256 threads x 4 queries ----
            const int mode = *mflag;
            const int qq0 = (bid - 1024) * 1024 + tid * 4;
            unsigned short mp[4];
            #pragma unroll
            for (int i = 0; i < 4; ++i) {
                const int qq = qq0 + i;
                unsigned bits = 0;
                if (mode & 2) {                      // byte-bool: 16 B per query
                    uint4 v = ((const uint4*)maskraw)[qq];
                    unsigned wds[4] = {v.x, v.y, v.z, v.w};
                    #pragma unroll
                    for (int wi = 0; wi < 4; ++wi)
                        #pragma unroll
                        for (int b = 0; b < 4; ++b)
                            if ((wds[wi] >> (8 * b)) & 0xFFu) bits |= 1u << (wi * 4 + b);
                } else {                             // int32 or f32: 64 B per query
                    const uint4* p = (const uint4*)maskraw + (size_t)qq * 4;
                    #pragma unroll
                    for (int wi = 0; wi < 4; ++wi) {
                        uint4 v = p[wi];
                        bits |= (v.x ? 1u : 0u) << (wi * 4 + 0);
                        bits |= (v.y ? 1u : 0u) << (wi * 4 + 1);
                        bits |= (v.z ? 1u : 0u) << (wi * 4 + 2);
                        bits |= (v.w ? 1u : 0u) << (wi * 4 + 3);
                    }
                }
                mp[i] = (unsigned short)bits;
            }
            ushort4 o4; o4.x = mp[0]; o4.y = mp[1]; o4.z = mp[2]; o4.w = mp[3];
            *(ushort4*)&mask_packed[qq0] = o4;
        } else {
            // ---- weight conversion: fp32 -> f16 transposed+padded ----
            const float* Ws[4] = {Wg1, Wg2, Wv, Wt};
            #pragma unroll
            for (int mat = 0; mat < 4; ++mat) {
                const float* W = Ws[mat];
                _Float16* dst = w4 + mat * 64 * 72;
                for (int i = tid; i < 4096; i += 256) {
                    int rr = i >> 6, c = i & 63;
                    dst[c * 72 + rr] = (_Float16)W[i];
                }
            }
        }
        return;
    }

    __shared__ __align__(16) _Float16 A_s[128 * 72];
    __shared__ __align__(16) _Float16 WT_s[64 * 72];

    const int r0 = bid * 128;
    const float* x; const float* p; _Float16* o; int rb;
    if (r0 < MQ) { x = q; p = qpos; o = qp_h; rb = r0; }
    else         { x = k; p = kpos; o = kp_h; rb = r0 - MQ; }

    #pragma unroll
    for (int j = 0; j < 4; ++j) {
        int i = (tid + j * 256) * 4;
        int rr = i >> 6, c4 = i & 63;
        floatx4 wv = *(const floatx4*)&Wqk[i];
        WT_s[(c4 + 0) * 72 + rr] = (_Float16)wv.x;
        WT_s[(c4 + 1) * 72 + rr] = (_Float16)wv.y;
        WT_s[(c4 + 2) * 72 + rr] = (_Float16)wv.z;
        WT_s[(c4 + 3) * 72 + rr] = (_Float16)wv.w;
    }
    #pragma unroll
    for (int j = 0; j < 8; ++j) {
        int flat = tid + j * 256;              // float4 id 0..2047
        int rr = flat >> 4, c4 = (flat & 15) * 4;
        size_t g = (size_t)(rb + rr) * 64 + c4;
        floatx4 xv = *(const floatx4*)&x[g];
        floatx4 pv = *(const floatx4*)&p[g];
        half4v h;
        h[0] = (_Float16)(xv.x + pv.x); h[1] = (_Float16)(xv.y + pv.y);
        h[2] = (_Float16)(xv.z + pv.z); h[3] = (_Float16)(xv.w + pv.w);
        *(half4v*)&A_s[rr * 72 + c4] = h;
    }
    __syncthreads();

    const int w = tid >> 6, lane = tid & 63, m = lane & 15, qd = lane >> 4;
    const floatx4 fz = {0.f, 0.f, 0.f, 0.f};
    floatx4 acc[2][4];
    #pragma unroll
    for (int rt = 0; rt < 2; rt++)
        #pragma unroll
        for (int ct = 0; ct < 4; ct++) acc[rt][ct] = fz;

    #pragma unroll
    for (int kc = 0; kc < 2; ++kc) {
        const int k0 = kc * 32 + qd * 8;
        half8 b[4];
        #pragma unroll
        for (int ct = 0; ct < 4; ++ct)
            b[ct] = *(const half8*)&WT_s[(ct * 16 + m) * 72 + k0];
        #pragma unroll
        for (int rt = 0; rt < 2; ++rt) {
            half8 a = *(const half8*)&A_s[(w * 32 + rt * 16 + m) * 72 + k0];
            #pragma unroll
            for (int ct = 0; ct < 4; ++ct)
                acc[rt][ct] = __builtin_amdgcn_mfma_f32_16x16x32_f16(a, b[ct], acc[rt][ct], 0, 0, 0);
        }
    }
    #pragma unroll
    for (int rt = 0; rt < 2; rt++)
        #pragma unroll
        for (int ct = 0; ct < 4; ct++) {
            const int col = ct * 16 + m;
            const float bb = bqk[col];
            #pragma unroll
            for (int rg = 0; rg < 4; ++rg) {
                const int row = w * 32 + rt * 16 + qd * 4 + rg;
                A_s[row * 72 + col] = (_Float16)(acc[rt][ct][rg] + bb);
            }
        }
    __syncthreads();
    #pragma unroll
    for (int j = 0; j < 4; ++j) {
        int ch = tid + j * 256;                // 16B chunk id, 0..1023
        int rr = ch >> 3, off = (ch & 7) * 8;
        *(half8*)&o[(size_t)(rb + rr) * 64 + off] = *(const half8*)&A_s[rr * 72 + off];
    }
}

// ---------------- persistent fused edge-MLP + softmax + aggregate ----------------
__global__ __launch_bounds__(256, 2)
void cross_attn(const float* __restrict__ value, const unsigned short* __restrict__ mask_packed,
                const int* __restrict__ idx,
                const _Float16* __restrict__ qp_h, const _Float16* __restrict__ kp_h,
                const _Float16* __restrict__ w4,
                const float* __restrict__ bg1, const float* __restrict__ bg2,
                const float* __restrict__ bv,
                _Float16* __restrict__ res_g)
{
    __shared__ __align__(16) _Float16 W3_s[3 * 64 * 72];  // Wg1T, Wg2T, WvT
    __shared__ __align__(16) _Float16 H_s[256 * 72];      // wave-private 64-row regions

    const int tid = threadIdx.x, w = tid >> 6, lane = tid & 63, m = lane & 15, qd = tid >> 4 & 3;
    const int tile0 = blockIdx.x * TPB;

    // weight staging (once per block)
    for (int ch = tid; ch < 1728; ch += 256)
        *(half8*)&W3_s[ch * 8] = *(const half8*)&w4[ch * 8];

    float bg1v[4], bg2v[4], bvv[4];
    #pragma unroll
    for (int ct = 0; ct < 4; ct++) {
        const int col = ct * 16 + m;
        bg1v[ct] = bg1[col]; bg2v[ct] = bg2[col]; bvv[ct] = bv[col];
    }

    // ---- prologue: issue tile-0 loads ----
    int idxr[4]; unsigned mpr[4];
    half8 qpr[4][2], kpr[4][2];
    floatx4 vraw[16];
    {
        const int q0 = tile0 * 16;
        #pragma unroll
        for (int rt = 0; rt < 4; ++rt) {
            const int qrow = q0 + w * 4 + rt;
            idxr[rt] = idx[qrow * KNB + m];
            mpr[rt]  = mask_packed[qrow];
            #pragma unroll
            for (int kc = 0; kc < 2; ++kc)
                qpr[rt][kc] = *(const half8*)&qp_h[(size_t)qrow * 64 + kc * 32 + qd * 8];
            #pragma unroll
            for (int kc = 0; kc < 2; ++kc) {
                const float* vr = value + ((size_t)qrow * KNB + m) * 64 + kc * 32 + qd * 8;
                vraw[(rt * 2 + kc) * 2 + 0] = *(const floatx4*)vr;
                vraw[(rt * 2 + kc) * 2 + 1] = *(const floatx4*)(vr + 4);
            }
        }
        #pragma unroll
        for (int rt = 0; rt < 4; ++rt)
            #pragma unroll
            for (int kc = 0; kc < 2; ++kc)
                kpr[rt][kc] = *(const half8*)&kp_h[(size_t)idxr[rt] * 64 + kc * 32 + qd * 8];
    }
    __syncthreads();   // weights ready; ONLY barrier

    const _Float16* Wg1T = W3_s;
    const _Float16* Wg2T = W3_s + 4608;
    const _Float16* WvT  = W3_s + 2 * 4608;
    const floatx4 fz = {0.f, 0.f, 0.f, 0.f};

    for (int t = 0; t < TPB; ++t) {
        const int q0t = (tile0 + t) * 16;
        const bool more = (t + 1 < TPB);
        unsigned mcur[4];
        #pragma unroll
        for (int rt = 0; rt < 4; ++rt) mcur[rt] = mpr[rt];

        // value(t) fp32 -> f16 frags
        half8 vfrag[8];
        #pragma unroll
        for (int f = 0; f < 8; ++f) {
            floatx4 x0 = vraw[f * 2], x1 = vraw[f * 2 + 1];
            half8 a;
            #pragma unroll
            for (int j = 0; j < 4; ++j) { a[j] = (_Float16)x0[j]; a[4 + j] = (_Float16)x1[j]; }
            vfrag[f] = a;
        }

        // ---- h = relu(d @ Wg1 + b), d-frags formed in registers ----
        floatx4 acch[4][4];
        #pragma unroll
        for (int rt = 0; rt < 4; rt++)
            #pragma unroll
            for (int ct = 0; ct < 4; ct++) acch[rt][ct] = fz;
        #pragma unroll
        for (int kc = 0; kc < 2; ++kc) {
            const int k0 = kc * 32 + qd * 8;
            half8 b[4];
            #pragma unroll
            for (int ct = 0; ct < 4; ++ct)
                b[ct] = *(const half8*)&Wg1T[(ct * 16 + m) * 72 + k0];
            #pragma unroll
            for (int rt = 0; rt < 4; ++rt) {
                half8 a = qpr[rt][kc] - kpr[rt][kc];
                #pragma unroll
                for (int ct = 0; ct < 4; ++ct)
                    acch[rt][ct] = __builtin_amdgcn_mfma_f32_16x16x32_f16(a, b[ct], acch[rt][ct], 0, 0, 0);
            }
        }

        // ---- issue next-tile loads (value, idx, qp, mask) ----
        int idxn[4];
        if (more) {
            const int q0n = (tile0 + t + 1) * 16;
            #pragma unroll
            for (int rt = 0; rt < 4; ++rt) {
                const int qrow = q0n + w * 4 + rt;
                idxn[rt] = idx[qrow * KNB + m];
                mpr[rt]  = mask_packed[qrow];
                #pragma unroll
                for (int kc = 0; kc < 2; ++kc)
                    qpr[rt][kc] = *(const half8*)&qp_h[(size_t)qrow * 64 + kc * 32 + qd * 8];
                #pragma unroll
                for (int kc = 0; kc < 2; ++kc) {
                    const float* vr = value + ((size_t)qrow * KNB + m) * 64 + kc * 32 + qd * 8;
                    vraw[(rt * 2 + kc) * 2 + 0] = *(const floatx4*)vr;
                    vraw[(rt * 2 + kc) * 2 + 1] = *(const floatx4*)(vr + 4);
                }
            }
        }

        // ---- h -> wave-private LDS, then e = h @ Wg2 ----
        #pragma unroll
        for (int rt = 0; rt < 4; rt++)
            #pragma unroll
            for (int ct = 0; ct < 4; ct++) {
                const int col = ct * 16 + m;
                #pragma unroll
                for (int rg = 0; rg < 4; ++rg) {
                    const int row = w * 64 + rt * 16 + qd * 4 + rg;
                    float h = acch[rt][ct][rg] + bg1v[ct];
                    H_s[row * 72 + col] = (_Float16)fmaxf(h, 0.f);
                }
            }
        __asm__ volatile("s_waitcnt lgkmcnt(0)" ::: "memory");

        floatx4 acce[4][4];
        #pragma unroll
        for (int rt = 0; rt < 4; rt++)
            #pragma unroll
            for (int ct = 0; ct < 4; ct++) acce[rt][ct] = fz;
        #pragma unroll
        for (int kc = 0; kc < 2; ++kc) {
            const int k0 = kc * 32 + qd * 8;
            half8 b[4];
            #pragma unroll
            for (int ct = 0; ct < 4; ++ct)
                b[ct] = *(const half8*)&Wg2T[(ct * 16 + m) * 72 + k0];
            #pragma unroll
            for (int rt = 0; rt < 4; ++rt) {
                half8 a = *(const half8*)&H_s[(w * 64 + rt * 16 + m) * 72 + k0];
                #pragma unroll
                for (int ct = 0; ct < 4; ++ct)
                    acce[rt][ct] = __builtin_amdgcn_mfma_f32_16x16x32_f16(a, b[ct], acce[rt][ct], 0, 0, 0);
            }
        }

        // ---- issue next-tile kp gather (depends on idxn) ----
        if (more) {
            #pragma unroll
            for (int rt = 0; rt < 4; ++rt)
                #pragma unroll
                for (int kc = 0; kc < 2; ++kc)
                    kpr[rt][kc] = *(const half8*)&kp_h[(size_t)idxn[rt] * 64 + kc * 32 + qd * 8];
        }

        // ---- v = value @ Wv ----
        floatx4 accv[4][4];
        #pragma unroll
        for (int rt = 0; rt < 4; rt++)
            #pragma unroll
            for (int ct = 0; ct < 4; ct++) accv[rt][ct] = fz;
        #pragma unroll
        for (int kc = 0; kc < 2; ++kc) {
            const int k0 = kc * 32 + qd * 8;
            half8 b[4];
            #pragma unroll
            for (int ct = 0; ct < 4; ++ct)
                b[ct] = *(const half8*)&WvT[(ct * 16 + m) * 72 + k0];
            #pragma unroll
            for (int rt = 0; rt < 4; ++rt) {
                half8 a = vfrag[rt * 2 + kc];
                #pragma unroll
                for (int ct = 0; ct < 4; ++ct)
                    accv[rt][ct] = __builtin_amdgcn_mfma_f32_16x16x32_f16(a, b[ct], accv[rt][ct], 0, 0, 0);
            }
        }

        // ---- mask, softmax over 16 neighbors, aggregate, store res (f16) ----
        #pragma unroll
        for (int rt = 0; rt < 4; rt++) {
            float tca[4];
            #pragma unroll
            for (int ct = 0; ct < 4; ct++) {
                float ev[4];
                #pragma unroll
                for (int rg = 0; rg < 4; ++rg) {
                    float e = acce[rt][ct][rg] + bg2v[ct];
                    ev[rg] = ((mcur[rt] >> (qd * 4 + rg)) & 1u) ? -1e12f : e;
                }
                float mx = fmaxf(fmaxf(ev[0], ev[1]), fmaxf(ev[2], ev[3]));
                mx = fmaxf(mx, __shfl_xor(mx, 16));
                mx = fmaxf(mx, __shfl_xor(mx, 32));
                float pp[4], s = 0.f;
                #pragma unroll
                for (int rg = 0; rg < 4; ++rg) { pp[rg] = __expf(ev[rg] - mx); s += pp[rg]; }
                s += __shfl_xor(s, 16);
                s += __shfl_xor(s, 32);
                const float inv = 1.f / s;
                float tt = 0.f;
                #pragma unroll
                for (int rg = 0; rg < 4; ++rg)
                    tt += pp[rg] * inv * (accv[rt][ct][rg] + bvv[ct]);
                tt += __shfl_xor(tt, 16);
                tt += __shfl_xor(tt, 32);
                tca[ct] = tt;
            }
            // col = qd*16 + m = lane -> contiguous 128B store per rt
            float tsel = (qd == 0) ? tca[0] : (qd == 1) ? tca[1] : (qd == 2) ? tca[2] : tca[3];
            res_g[(size_t)(q0t + w * 4 + rt) * 64 + lane] = (_Float16)tsel;
        }
    }
}

// ---------------- out = res @ Wt + bt ----------------
__global__ __launch_bounds__(256, 4)
void out_proj(const _Float16* __restrict__ res_g, const _Float16* __restrict__ w4,
              const float* __restrict__ bt, float* __restrict__ out)
{
    __shared__ __align__(16) _Float16 WtT_s[64 * 72];
    const int tid = threadIdx.x;
    const _Float16* WtT_g = w4 + 3 * 4608;
    for (int ch = tid; ch < 576; ch += 256)
        *(half8*)&WtT_s[ch * 8] = *(const half8*)&WtT_g[ch * 8];
    __syncthreads();

    const int w = tid >> 6, lane = tid & 63, m = lane & 15, qd = lane >> 4;
    const int rb = blockIdx.x * 256;
    const floatx4 fz = {0.f, 0.f, 0.f, 0.f};
    float btv[4];
    #pragma unroll
    for (int ct = 0; ct < 4; ++ct) btv[ct] = bt[ct * 16 + m];

    #pragma unroll
    for (int rt = 0; rt < 4; ++rt) {
        floatx4 acc[4] = {fz, fz, fz, fz};
        #pragma unroll
        for (int kc = 0; kc < 2; ++kc) {
            const int k0 = kc * 32 + qd * 8;
            half8 a = *(const half8*)&res_g[(size_t)(rb + w * 64 + rt * 16 + m) * 64 + k0];
            half8 b[4];
            #pragma unroll
            for (int ct = 0; ct < 4; ++ct)
                b[ct] = *(const half8*)&WtT_s[(ct * 16 + m) * 72 + k0];
            #pragma unroll
            for (int ct = 0; ct < 4; ++ct)
                acc[ct] = __builtin_amdgcn_mfma_f32_16x16x32_f16(a, b[ct], acc[ct], 0, 0, 0);
        }
        #pragma unroll
        for (int ct = 0; ct < 4; ++ct) {
            #pragma unroll
            for (int rg = 0; rg < 4; ++rg)
                out[(size_t)(rb + w * 64 + rt * 16 + qd * 4 + rg) * 64 + ct * 16 + m] = acc[ct][rg] + btv[ct];
        }
    }
}

extern "C" void kernel_launch(void* const* d_in, const int* in_sizes, int n_in,
                              void* d_out, int out_size, void* d_ws, size_t ws_size,
                              hipStream_t stream) {
    const float* q     = (const float*)d_in[0];
    const float* k     = (const float*)d_in[1];
    const float* value = (const float*)d_in[2];
    const float* q_pos = (const float*)d_in[3];
    const float* k_pos = (const float*)d_in[4];
    const unsigned char* mask = (const unsigned char*)d_in[5];
    const int* knn     = (const int*)d_in[6];
    // d_in[7] = k_num scalar (16)
    const float* Wqk = (const float*)d_in[8];
    const float* bqk = (const float*)d_in[9];
    const float* Wv  = (const float*)d_in[10];
    const float* bv  = (const float*)d_in[11];
    const float* Wg1 = (const float*)d_in[12];
    const float* bg1 = (const float*)d_in[13];
    const float* Wg2 = (const float*)d_in[14];
    const float* bg2 = (const float*)d_in[15];
    const float* Wt  = (const float*)d_in[16];
    const float* bt  = (const float*)d_in[17];
    float* out = (float*)d_out;

    _Float16* qp_h  = (_Float16*)d_ws;
    _Float16* kp_h  = qp_h + (size_t)MQ * CCH;
    _Float16* res_g = kp_h + (size_t)NKEY * CCH;
    _Float16* w4    = res_g + (size_t)MQ * CCH;
    unsigned short* mask_packed = (unsigned short*)(w4 + 4 * 64 * 72);
    int* mflag = (int*)(mask_packed + MQ);
    const int* idx = knn + (size_t)MQ * KNB;   // row 1 of knearest_idx

    detect_mask<<<1, 256, 0, stream>>>(mask, mflag);
    proj_prep<<<1089, 256, 0, stream>>>(q, q_pos, k, k_pos, Wqk, bqk,
                                        Wg1, Wg2, Wv, Wt, mask, mflag,
                                        qp_h, kp_h, w4, mask_packed);
    cross_attn<<<MQ / (16 * TPB), 256, 0, stream>>>(value, mask_packed, idx, qp_h, kp_h, w4,
                                                    bg1, bg2, bv, res_g);
    out_proj<<<MQ / 256, 256, 0, stream>>>(res_g, w4, bt, out);
}

// Round 5
// 501.002 us; speedup vs baseline: 1.3645x; 1.3645x over previous
//
#include <hip/hip_runtime.h>
#include <hip/hip_bf16.h>

#define MQ 65536
#define NKEY 65536
#define KNB 16
#define CCH 64
#define TPB 8   // tiles (of 16 queries) per cross_attn block

typedef _Float16 half8  __attribute__((ext_vector_type(8)));
typedef _Float16 half4v __attribute__((ext_vector_type(4)));
typedef float    floatx4 __attribute__((ext_vector_type(4)));

// ws layout:
//   qp_h [MQ*64] f16, kp_h [NKEY*64] f16, res_g [MQ*64] f16,
//   w4 [4*64*72] f16 (Wg1T,Wg2T,WvT,WtT; transposed, row stride 72),
//   mask_packed [MQ] u16, mflag int

// ---------------- mask dtype detect (1 block) ----------------
__global__ void detect_mask(const unsigned char* __restrict__ m, int* __restrict__ flag)
{
    __shared__ int sflags;
    if (threadIdx.x == 0) sflags = 0;
    __syncthreads();
    const uint4* m4 = (const uint4*)m;
    unsigned int orw = 0;
    #pragma unroll
    for (int it = 0; it < 4; ++it) {
        uint4 v = m4[threadIdx.x + it * 256];
        orw |= v.x | v.y | v.z | v.w;
    }
    int local = 0;
    if (orw & 0x000000FFu) local |= 1;
    if (orw & 0x0000FF00u) local |= 2;
    if (orw & 0xFFFF0000u) local |= 4;
    if (local) atomicOr(&sflags, local);
    __syncthreads();
    if (threadIdx.x == 0) *flag = sflags;
}

// ---------------- proj + mask-pack + weight conversion ----------------
__global__ __launch_bounds__(256, 4)
void proj_prep(const float* __restrict__ q, const float* __restrict__ qpos,
               const float* __restrict__ k, const float* __restrict__ kpos,
               const float* __restrict__ Wqk, const float* __restrict__ bqk,
               const float* __restrict__ Wg1, const float* __restrict__ Wg2,
               const float* __restrict__ Wv,  const float* __restrict__ Wt,
               const unsigned char* __restrict__ maskraw, const int* __restrict__ mflag,
               _Float16* __restrict__ qp_h, _Float16* __restrict__ kp_h,
               _Float16* __restrict__ w4, unsigned short* __restrict__ mask_packed)
{
    const int tid = threadIdx.x;
    const int bid = blockIdx.x;

    if (bid >= 1024) {
        if (bid < 1088) {
            const int mode = *mflag;
            const int qq0 = (bid - 1024) * 1024 + tid * 4;
            unsigned short mp[4];
            #pragma unroll
            for (int i = 0; i < 4; ++i) {
                const int qq = qq0 + i;
                unsigned bits = 0;
                if (mode & 2) {
                    uint4 v = ((const uint4*)maskraw)[qq];
                    unsigned wds[4] = {v.x, v.y, v.z, v.w};
                    #pragma unroll
                    for (int wi = 0; wi < 4; ++wi)
                        #pragma unroll
                        for (int b = 0; b < 4; ++b)
                            if ((wds[wi] >> (8 * b)) & 0xFFu) bits |= 1u << (wi * 4 + b);
                } else {
                    const uint4* p = (const uint4*)maskraw + (size_t)qq * 4;
                    #pragma unroll
                    for (int wi = 0; wi < 4; ++wi) {
                        uint4 v = p[wi];
                        bits |= (v.x ? 1u : 0u) << (wi * 4 + 0);
                        bits |= (v.y ? 1u : 0u) << (wi * 4 + 1);
                        bits |= (v.z ? 1u : 0u) << (wi * 4 + 2);
                        bits |= (v.w ? 1u : 0u) << (wi * 4 + 3);
                    }
                }
                mp[i] = (unsigned short)bits;
            }
            ushort4 o4; o4.x = mp[0]; o4.y = mp[1]; o4.z = mp[2]; o4.w = mp[3];
            *(ushort4*)&mask_packed[qq0] = o4;
        } else {
            const float* Ws[4] = {Wg1, Wg2, Wv, Wt};
            #pragma unroll
            for (int mat = 0; mat < 4; ++mat) {
                const float* W = Ws[mat];
                _Float16* dst = w4 + mat * 64 * 72;
                for (int i = tid; i < 4096; i += 256) {
                    int rr = i >> 6, c = i & 63;
                    dst[c * 72 + rr] = (_Float16)W[i];
                }
            }
        }
        return;
    }

    __shared__ __align__(16) _Float16 A_s[128 * 72];
    __shared__ __align__(16) _Float16 WT_s[64 * 72];

    const int r0 = bid * 128;
    const float* x; const float* p; _Float16* o; int rb;
    if (r0 < MQ) { x = q; p = qpos; o = qp_h; rb = r0; }
    else         { x = k; p = kpos; o = kp_h; rb = r0 - MQ; }

    #pragma unroll
    for (int j = 0; j < 4; ++j) {
        int i = (tid + j * 256) * 4;
        int rr = i >> 6, c4 = i & 63;
        floatx4 wv = *(const floatx4*)&Wqk[i];
        WT_s[(c4 + 0) * 72 + rr] = (_Float16)wv.x;
        WT_s[(c4 + 1) * 72 + rr] = (_Float16)wv.y;
        WT_s[(c4 + 2) * 72 + rr] = (_Float16)wv.z;
        WT_s[(c4 + 3) * 72 + rr] = (_Float16)wv.w;
    }
    #pragma unroll
    for (int j = 0; j < 8; ++j) {
        int flat = tid + j * 256;
        int rr = flat >> 4, c4 = (flat & 15) * 4;
        size_t g = (size_t)(rb + rr) * 64 + c4;
        floatx4 xv = *(const floatx4*)&x[g];
        floatx4 pv = *(const floatx4*)&p[g];
        half4v h;
        h[0] = (_Float16)(xv.x + pv.x); h[1] = (_Float16)(xv.y + pv.y);
        h[2] = (_Float16)(xv.z + pv.z); h[3] = (_Float16)(xv.w + pv.w);
        *(half4v*)&A_s[rr * 72 + c4] = h;
    }
    __syncthreads();

    const int w = tid >> 6, lane = tid & 63, m = lane & 15, qd = lane >> 4;
    const floatx4 fz = {0.f, 0.f, 0.f, 0.f};
    floatx4 acc[2][4];
    #pragma unroll
    for (int rt = 0; rt < 2; rt++)
        #pragma unroll
        for (int ct = 0; ct < 4; ct++) acc[rt][ct] = fz;

    #pragma unroll
    for (int kc = 0; kc < 2; ++kc) {
        const int k0 = kc * 32 + qd * 8;
        half8 b[4];
        #pragma unroll
        for (int ct = 0; ct < 4; ++ct)
            b[ct] = *(const half8*)&WT_s[(ct * 16 + m) * 72 + k0];
        #pragma unroll
        for (int rt = 0; rt < 2; ++rt) {
            half8 a = *(const half8*)&A_s[(w * 32 + rt * 16 + m) * 72 + k0];
            #pragma unroll
            for (int ct = 0; ct < 4; ++ct)
                acc[rt][ct] = __builtin_amdgcn_mfma_f32_16x16x32_f16(a, b[ct], acc[rt][ct], 0, 0, 0);
        }
    }
    #pragma unroll
    for (int rt = 0; rt < 2; rt++)
        #pragma unroll
        for (int ct = 0; ct < 4; ct++) {
            const int col = ct * 16 + m;
            const float bb = bqk[col];
            #pragma unroll
            for (int rg = 0; rg < 4; ++rg) {
                const int row = w * 32 + rt * 16 + qd * 4 + rg;
                A_s[row * 72 + col] = (_Float16)(acc[rt][ct][rg] + bb);
            }
        }
    __syncthreads();
    #pragma unroll
    for (int j = 0; j < 4; ++j) {
        int ch = tid + j * 256;
        int rr = ch >> 3, off = (ch & 7) * 8;
        *(half8*)&o[(size_t)(rb + rr) * 64 + off] = *(const half8*)&A_s[rr * 72 + off];
    }
}

// ---------------- persistent fused edge-MLP + softmax + aggregate ----------------
// Register budget pinned to 2 waves/EU (LDS caps occupancy there anyway) -> 256 VGPR/wave.
__global__ __launch_bounds__(256) __attribute__((amdgpu_waves_per_eu(2, 2)))
void cross_attn(const float* __restrict__ value, const unsigned short* __restrict__ mask_packed,
                const int* __restrict__ idx,
                const _Float16* __restrict__ qp_h, const _Float16* __restrict__ kp_h,
                const _Float16* __restrict__ w4,
                const float* __restrict__ bg1, const float* __restrict__ bg2,
                const float* __restrict__ bv,
                _Float16* __restrict__ res_g)
{
    __shared__ __align__(16) _Float16 W3_s[3 * 64 * 72];  // Wg1T, Wg2T, WvT
    __shared__ __align__(16) _Float16 H_s[256 * 72];      // wave-private 64-row regions

    const int tid = threadIdx.x, w = tid >> 6, lane = tid & 63, m = lane & 15, qd = (lane >> 4) & 3;
    const int tile0 = blockIdx.x * TPB;

    for (int ch = tid; ch < 1728; ch += 256)
        *(half8*)&W3_s[ch * 8] = *(const half8*)&w4[ch * 8];

    float bg1v[4], bg2v[4], bvv[4];
    #pragma unroll
    for (int ct = 0; ct < 4; ct++) {
        const int col = ct * 16 + m;
        bg1v[ct] = bg1[col]; bg2v[ct] = bg2[col]; bvv[ct] = bv[col];
    }

    // ---- prologue: tile-0 loads (value rolling buffer + idx/mask/qp one tile ahead) ----
    int idxn[4]; unsigned mpr[4];
    half8 qpr[4][2];
    floatx4 vraw[16];
    {
        const int q0 = tile0 * 16;
        #pragma unroll
        for (int rt = 0; rt < 4; ++rt) {
            const int qrow = q0 + w * 4 + rt;
            idxn[rt] = idx[qrow * KNB + m];
            mpr[rt]  = mask_packed[qrow];
            #pragma unroll
            for (int kc = 0; kc < 2; ++kc)
                qpr[rt][kc] = *(const half8*)&qp_h[(size_t)qrow * 64 + kc * 32 + qd * 8];
            #pragma unroll
            for (int kc = 0; kc < 2; ++kc) {
                const float* vr = value + ((size_t)qrow * KNB + m) * 64 + kc * 32 + qd * 8;
                vraw[(rt * 2 + kc) * 2 + 0] = *(const floatx4*)vr;
                vraw[(rt * 2 + kc) * 2 + 1] = *(const floatx4*)(vr + 4);
            }
        }
    }
    __syncthreads();   // weights ready; ONLY barrier

    const _Float16* Wg1T = W3_s;
    const _Float16* Wg2T = W3_s + 4608;
    const _Float16* WvT  = W3_s + 2 * 4608;
    const floatx4 fz = {0.f, 0.f, 0.f, 0.f};

    for (int t = 0; t < TPB; ++t) {
        const int q0t = (tile0 + t) * 16;
        const bool more = (t + 1 < TPB);

        unsigned mcur[4];
        #pragma unroll
        for (int rt = 0; rt < 4; ++rt) mcur[rt] = mpr[rt];

        // ---- kp gather for all 4 queries (idx prefetched last tile) ----
        half8 kpr[4][2];
        #pragma unroll
        for (int rt = 0; rt < 4; ++rt)
            #pragma unroll
            for (int kc = 0; kc < 2; ++kc)
                kpr[rt][kc] = *(const half8*)&kp_h[(size_t)idxn[rt] * 64 + kc * 32 + qd * 8];

        // ---- process queries in pairs (register diet: 32-reg accumulator sets) ----
        #pragma unroll
        for (int pr = 0; pr < 2; ++pr) {
            const int r0 = pr * 2;

            // value(t) frags for this pair (waits on rolling buffer loads)
            half8 vfrag[2][2];
            #pragma unroll
            for (int rr = 0; rr < 2; ++rr)
                #pragma unroll
                for (int kc = 0; kc < 2; ++kc) {
                    floatx4 x0 = vraw[((r0 + rr) * 2 + kc) * 2 + 0];
                    floatx4 x1 = vraw[((r0 + rr) * 2 + kc) * 2 + 1];
                    half8 a;
                    #pragma unroll
                    for (int j = 0; j < 4; ++j) { a[j] = (_Float16)x0[j]; a[4 + j] = (_Float16)x1[j]; }
                    vfrag[rr][kc] = a;
                }

            // v = value @ Wv for pair
            floatx4 accv2[2][4];
            #pragma unroll
            for (int rr = 0; rr < 2; ++rr)
                #pragma unroll
                for (int ct = 0; ct < 4; ++ct) accv2[rr][ct] = fz;
            #pragma unroll
            for (int kc = 0; kc < 2; ++kc) {
                const int k0 = kc * 32 + qd * 8;
                half8 b[4];
                #pragma unroll
                for (int ct = 0; ct < 4; ++ct)
                    b[ct] = *(const half8*)&WvT[(ct * 16 + m) * 72 + k0];
                #pragma unroll
                for (int rr = 0; rr < 2; ++rr)
                    #pragma unroll
                    for (int ct = 0; ct < 4; ++ct)
                        accv2[rr][ct] = __builtin_amdgcn_mfma_f32_16x16x32_f16(vfrag[rr][kc], b[ct], accv2[rr][ct], 0, 0, 0);
            }

            // refill this pair's vraw slots with tile t+1 (in-flight ~ one full tile)
            if (more) {
                const int q0n = q0t + 16;
                #pragma unroll
                for (int rr = 0; rr < 2; ++rr) {
                    const int qrow = q0n + w * 4 + r0 + rr;
                    #pragma unroll
                    for (int kc = 0; kc < 2; ++kc) {
                        const float* vr = value + ((size_t)qrow * KNB + m) * 64 + kc * 32 + qd * 8;
                        vraw[((r0 + rr) * 2 + kc) * 2 + 0] = *(const floatx4*)vr;
                        vraw[((r0 + rr) * 2 + kc) * 2 + 1] = *(const floatx4*)(vr + 4);
                    }
                }
            }

            // h = relu(d @ Wg1 + b) for pair, d-frags in registers
            floatx4 acch2[2][4];
            #pragma unroll
            for (int rr = 0; rr < 2; ++rr)
                #pragma unroll
                for (int ct = 0; ct < 4; ++ct) acch2[rr][ct] = fz;
            #pragma unroll
            for (int kc = 0; kc < 2; ++kc) {
                const int k0 = kc * 32 + qd * 8;
                half8 b[4];
                #pragma unroll
                for (int ct = 0; ct < 4; ++ct)
                    b[ct] = *(const half8*)&Wg1T[(ct * 16 + m) * 72 + k0];
                #pragma unroll
                for (int rr = 0; rr < 2; ++rr) {
                    half8 a = qpr[r0 + rr][kc] - kpr[r0 + rr][kc];
                    #pragma unroll
                    for (int ct = 0; ct < 4; ++ct)
                        acch2[rr][ct] = __builtin_amdgcn_mfma_f32_16x16x32_f16(a, b[ct], acch2[rr][ct], 0, 0, 0);
                }
            }

            // h -> wave-private LDS
            #pragma unroll
            for (int rr = 0; rr < 2; ++rr)
                #pragma unroll
                for (int ct = 0; ct < 4; ++ct) {
                    const int col = ct * 16 + m;
                    #pragma unroll
                    for (int rg = 0; rg < 4; ++rg) {
                        const int row = w * 64 + (r0 + rr) * 16 + qd * 4 + rg;
                        float h = acch2[rr][ct][rg] + bg1v[ct];
                        H_s[row * 72 + col] = (_Float16)fmaxf(h, 0.f);
                    }
                }
            __asm__ volatile("s_waitcnt lgkmcnt(0)" ::: "memory");

            // e = h @ Wg2 for pair
            floatx4 acce2[2][4];
            #pragma unroll
            for (int rr = 0; rr < 2; ++rr)
                #pragma unroll
                for (int ct = 0; ct < 4; ++ct) acce2[rr][ct] = fz;
            #pragma unroll
            for (int kc = 0; kc < 2; ++kc) {
                const int k0 = kc * 32 + qd * 8;
                half8 b[4];
                #pragma unroll
                for (int ct = 0; ct < 4; ++ct)
                    b[ct] = *(const half8*)&Wg2T[(ct * 16 + m) * 72 + k0];
                #pragma unroll
                for (int rr = 0; rr < 2; ++rr) {
                    half8 a = *(const half8*)&H_s[(w * 64 + (r0 + rr) * 16 + m) * 72 + k0];
                    #pragma unroll
                    for (int ct = 0; ct < 4; ++ct)
                        acce2[rr][ct] = __builtin_amdgcn_mfma_f32_16x16x32_f16(a, b[ct], acce2[rr][ct], 0, 0, 0);
                }
            }

            // after pair 0: prefetch next tile's idx + mask (qp still in use by pair 1)
            if (pr == 0 && more) {
                const int q0n = q0t + 16;
                #pragma unroll
                for (int rt = 0; rt < 4; ++rt) {
                    const int qrow = q0n + w * 4 + rt;
                    idxn[rt] = idx[qrow * KNB + m];
                    mpr[rt]  = mask_packed[qrow];
                }
            }

            // softmax over 16 neighbors + aggregate + res store (f16)
            #pragma unroll
            for (int rr = 0; rr < 2; ++rr) {
                const int rt = r0 + rr;
                float tca[4];
                #pragma unroll
                for (int ct = 0; ct < 4; ++ct) {
                    float ev[4];
                    #pragma unroll
                    for (int rg = 0; rg < 4; ++rg) {
                        float e = acce2[rr][ct][rg] + bg2v[ct];
                        ev[rg] = ((mcur[rt] >> (qd * 4 + rg)) & 1u) ? -1e12f : e;
                    }
                    float mx = fmaxf(fmaxf(ev[0], ev[1]), fmaxf(ev[2], ev[3]));
                    mx = fmaxf(mx, __shfl_xor(mx, 16));
                    mx = fmaxf(mx, __shfl_xor(mx, 32));
                    float pp[4], s = 0.f;
                    #pragma unroll
                    for (int rg = 0; rg < 4; ++rg) { pp[rg] = __expf(ev[rg] - mx); s += pp[rg]; }
                    s += __shfl_xor(s, 16);
                    s += __shfl_xor(s, 32);
                    const float inv = 1.f / s;
                    float tt = 0.f;
                    #pragma unroll
                    for (int rg = 0; rg < 4; ++rg)
                        tt += pp[rg] * inv * (accv2[rr][ct][rg] + bvv[ct]);
                    tt += __shfl_xor(tt, 16);
                    tt += __shfl_xor(tt, 32);
                    tca[ct] = tt;
                }
                float tsel = (qd == 0) ? tca[0] : (qd == 1) ? tca[1] : (qd == 2) ? tca[2] : tca[3];
                res_g[(size_t)(q0t + w * 4 + rt) * 64 + lane] = (_Float16)tsel;
            }
        }

        // after pair 1: prefetch next tile's qp
        if (more) {
            const int q0n = q0t + 16;
            #pragma unroll
            for (int rt = 0; rt < 4; ++rt) {
                const int qrow = q0n + w * 4 + rt;
                #pragma unroll
                for (int kc = 0; kc < 2; ++kc)
                    qpr[rt][kc] = *(const half8*)&qp_h[(size_t)qrow * 64 + kc * 32 + qd * 8];
            }
        }
    }
}

// ---------------- out = res @ Wt + bt ----------------
__global__ __launch_bounds__(256, 4)
void out_proj(const _Float16* __restrict__ res_g, const _Float16* __restrict__ w4,
              const float* __restrict__ bt, float* __restrict__ out)
{
    __shared__ __align__(16) _Float16 WtT_s[64 * 72];
    const int tid = threadIdx.x;
    const _Float16* WtT_g = w4 + 3 * 4608;
    for (int ch = tid; ch < 576; ch += 256)
        *(half8*)&WtT_s[ch * 8] = *(const half8*)&WtT_g[ch * 8];
    __syncthreads();

    const int w = tid >> 6, lane = tid & 63, m = lane & 15, qd = lane >> 4;
    const int rb = blockIdx.x * 256;
    const floatx4 fz = {0.f, 0.f, 0.f, 0.f};
    float btv[4];
    #pragma unroll
    for (int ct = 0; ct < 4; ++ct) btv[ct] = bt[ct * 16 + m];

    #pragma unroll
    for (int rt = 0; rt < 4; ++rt) {
        floatx4 acc[4] = {fz, fz, fz, fz};
        #pragma unroll
        for (int kc = 0; kc < 2; ++kc) {
            const int k0 = kc * 32 + qd * 8;
            half8 a = *(const half8*)&res_g[(size_t)(rb + w * 64 + rt * 16 + m) * 64 + k0];
            half8 b[4];
            #pragma unroll
            for (int ct = 0; ct < 4; ++ct)
                b[ct] = *(const half8*)&WtT_s[(ct * 16 + m) * 72 + k0];
            #pragma unroll
            for (int ct = 0; ct < 4; ++ct)
                acc[ct] = __builtin_amdgcn_mfma_f32_16x16x32_f16(a, b[ct], acc[ct], 0, 0, 0);
        }
        #pragma unroll
        for (int ct = 0; ct < 4; ++ct) {
            #pragma unroll
            for (int rg = 0; rg < 4; ++rg)
                out[(size_t)(rb + w * 64 + rt * 16 + qd * 4 + rg) * 64 + ct * 16 + m] = acc[ct][rg] + btv[ct];
        }
    }
}

extern "C" void kernel_launch(void* const* d_in, const int* in_sizes, int n_in,
                              void* d_out, int out_size, void* d_ws, size_t ws_size,
                              hipStream_t stream) {
    const float* q     = (const float*)d_in[0];
    const float* k     = (const float*)d_in[1];
    const float* value = (const float*)d_in[2];
    const float* q_pos = (const float*)d_in[3];
    const float* k_pos = (const float*)d_in[4];
    const unsigned char* mask = (const unsigned char*)d_in[5];
    const int* knn     = (const int*)d_in[6];
    // d_in[7] = k_num scalar (16)
    const float* Wqk = (const float*)d_in[8];
    const float* bqk = (const float*)d_in[9];
    const float* Wv  = (const float*)d_in[10];
    const float* bv  = (const float*)d_in[11];
    const float* Wg1 = (const float*)d_in[12];
    const float* bg1 = (const float*)d_in[13];
    const float* Wg2 = (const float*)d_in[14];
    const float* bg2 = (const float*)d_in[15];
    const float* Wt  = (const float*)d_in[16];
    const float* bt  = (const float*)d_in[17];
    float* out = (float*)d_out;

    _Float16* qp_h  = (_Float16*)d_ws;
    _Float16* kp_h  = qp_h + (size_t)MQ * CCH;
    _Float16* res_g = kp_h + (size_t)NKEY * CCH;
    _Float16* w4    = res_g + (size_t)MQ * CCH;
    unsigned short* mask_packed = (unsigned short*)(w4 + 4 * 64 * 72);
    int* mflag = (int*)(mask_packed + MQ);
    const int* idx = knn + (size_t)MQ * KNB;   // row 1 of knearest_idx

    detect_mask<<<1, 256, 0, stream>>>(mask, mflag);
    proj_prep<<<1089, 256, 0, stream>>>(q, q_pos, k, k_pos, Wqk, bqk,
                                        Wg1, Wg2, Wv, Wt, mask, mflag,
                                        qp_h, kp_h, w4, mask_packed);
    cross_attn<<<MQ / (16 * TPB), 256, 0, stream>>>(value, mask_packed, idx, qp_h, kp_h, w4,
                                                    bg1, bg2, bv, res_g);
    out_proj<<<MQ / 256, 256, 0, stream>>>(res_g, w4, bt, out);
}